// Round 9
// baseline (145.301 us; speedup 1.0000x reference)
//
#include <hip/hip_runtime.h>

typedef __bf16 bf16_t;
typedef __attribute__((ext_vector_type(2))) __bf16 bf16x2;
typedef __attribute__((ext_vector_type(4))) __bf16 bf16x4;
typedef __attribute__((ext_vector_type(8))) __bf16 bf16x8;
typedef __attribute__((ext_vector_type(4))) float f32x4;
typedef __attribute__((ext_vector_type(16))) float f32x16;

#define MFMA16(a, b, c) __builtin_amdgcn_mfma_f32_16x16x32_bf16((a), (b), (c), 0, 0, 0)
#define MFMA32(a, b, c) __builtin_amdgcn_mfma_f32_32x32x16_bf16((a), (b), (c), 0, 0, 0)

// Problem: B=8 S=1024 D=768 H=16 Dh=64 OD=1024, M = B*S = 8192
// xf: x in A-fragment order  (8192x768):  chunk(m16,kt) elem: lane l <- x[m16*16+(l&15)][kt*32+(l>>4)*8+j]
// wf: wT in B-fragment order (3x1024x768): chunk(n16,kt) elem: lane l <- wT[n16*16+(l&15)][kt*32+(l>>4)*8+j]
static constexpr unsigned XB_OFF = 0u;                          // xf bf16: 12,582,912
static constexpr unsigned WT_OFF = 12582912u;                   // wf bf16: 4,718,592
static constexpr unsigned Q_OFF  = WT_OFF + 4718592u;           // Qf bf16: 16,777,216
static constexpr unsigned K_OFF  = Q_OFF + 16777216u;
static constexpr unsigned VT_OFF = K_OFF + 16777216u;           // end = 67,633,152

// ---------------- merged cast kernel ----------------
// blocks [0,6144): x f32 -> bf16 A-fragment order (float4/thread)
// blocks [6144,8448): w f32 -> wT bf16 B-fragment order; q_w scaled by
// 0.125*log2(e) = 0.18033688 (attention 1/8 and exp2 conversion folded in).
__global__ __launch_bounds__(256) void cast_kernel(const float4* __restrict__ x4,
                                                   bf16_t* __restrict__ xf,
                                                   const float* __restrict__ qw,
                                                   const float* __restrict__ kw,
                                                   const float* __restrict__ vw,
                                                   bf16_t* __restrict__ wf) {
    if (blockIdx.x < 6144u) {
        unsigned i = blockIdx.x * 256u + threadIdx.x;
        float4 v = x4[i];
        unsigned m = i / 192u, k4 = i % 192u;           // 4 consecutive k at 4*k4
        bf16x4 o;
        o[0] = (bf16_t)v.x; o[1] = (bf16_t)v.y; o[2] = (bf16_t)v.z; o[3] = (bf16_t)v.w;
        unsigned chunk = (m >> 4) * 24u + (k4 >> 3);
        unsigned off = ((m & 15u) + 16u * ((k4 & 7u) >> 1)) * 8u + (k4 & 1u) * 4u;
        *(bf16x4*)&xf[chunk * 512u + off] = o;
    } else {
        unsigned t = (blockIdx.x - 6144u) * 256u + threadIdx.x;
        unsigned w  = t / 196608u;
        unsigned r  = t % 196608u;
        unsigned n  = r % 1024u;                        // wT row (output col)
        unsigned k4 = r / 1024u;
        const float* src = (w == 0u) ? qw : (w == 1u) ? kw : vw;
        float s = (w == 0u) ? 0.18033688011112043f : 1.0f;
        bf16x4 o;
#pragma unroll
        for (int i = 0; i < 4; ++i) o[i] = (bf16_t)(src[(k4 * 4u + i) * 1024u + n] * s);
        unsigned chunk = (n >> 4) * 24u + (k4 >> 3);
        unsigned off = ((n & 15u) + 16u * ((k4 & 7u) >> 1)) * 8u + (k4 & 1u) * 4u;
        *(bf16x4*)&wf[w * 786432u + chunk * 512u + off] = o;
    }
}

// ---------------- fused QKV projection GEMM, LDS-FREE fragment streaming ----
// Both operands pre-laid-out in MFMA fragment order: per K-step each wave does
// 8 coalesced 1KB global loads + 16 MFMA. No LDS, no barriers, no waitcnt asm
// -- waves fully independent (the structure that made attn fast). Reuse via
// L1 (A shared by wn-pair, B by wm-pair in-block) and per-XCD L2 (work remap:
// 1536 = 8 XCDs x 192 contiguous works; A-panel + 1.5MB wsel-weights stay hot).
// __launch_bounds__(256,4): cap VGPR at 128 -> 16 waves/CU.
__global__ __launch_bounds__(256, 4) void proj_kernel(const bf16_t* __restrict__ xf,
                                                      const bf16_t* __restrict__ wf,
                                                      bf16_t* __restrict__ q,
                                                      bf16_t* __restrict__ k,
                                                      bf16_t* __restrict__ vt) {
    const int id = blockIdx.x;
    const int work = (id & 7) * 192 + (id >> 3);        // bijective, 1536 = 8*192
    const int nb = work & 7, mb = (work >> 3) & 63, wsel = work >> 9;
    const int t = threadIdx.x;
    const int w = t >> 6, l = t & 63;
    const int lo = l & 15, hi = l >> 4;
    const int wm = w >> 1, wn = w & 1;                  // 2x2 waves, 64x64 each
    const bf16_t* abase = xf + (unsigned)((mb * 8 + wm * 4) * 24) * 512u + l * 8;
    const bf16_t* bbase = wf + wsel * 786432u + (unsigned)((nb * 8 + wn * 4) * 24) * 512u + l * 8;

    f32x4 acc[4][4];
#pragma unroll
    for (int m = 0; m < 4; ++m)
#pragma unroll
        for (int n = 0; n < 4; ++n)
#pragma unroll
            for (int i = 0; i < 4; ++i) acc[m][n][i] = 0.f;

    for (int kt = 0; kt < 24; ++kt) {
        bf16x8 af[4], bfr[4];
#pragma unroll
        for (int m_ = 0; m_ < 4; ++m_)
            af[m_] = *(const bf16x8*)(abase + (unsigned)(m_ * 24 + kt) * 512u);
#pragma unroll
        for (int n_ = 0; n_ < 4; ++n_)
            bfr[n_] = *(const bf16x8*)(bbase + (unsigned)(n_ * 24 + kt) * 512u);
        __builtin_amdgcn_s_setprio(1);
#pragma unroll
        for (int m_ = 0; m_ < 4; ++m_)
#pragma unroll
            for (int n_ = 0; n_ < 4; ++n_)
                acc[m_][n_] = MFMA16(af[m_], bfr[n_], acc[m_][n_]);
        __builtin_amdgcn_s_setprio(0);
    }

    // epilogue: scatter to fragment-order Qf/Kf/Vf layouts (unchanged math)
    const int rbase = mb * 128 + wm * 64;
    const int cbase = nb * 128 + wn * 64;
#pragma unroll
    for (int m = 0; m < 4; ++m) {
#pragma unroll
        for (int n = 0; n < 4; ++n) {
#pragma unroll
            for (int r = 0; r < 4; ++r) {
                int mrow = rbase + m * 16 + hi * 4 + r;   // C/D: row=(l>>4)*4+r
                int ncol = cbase + n * 16 + lo;           //      col=l&15
                int bb = mrow >> 10, ss = mrow & 1023;    // ss = seq pos
                int hh = ncol >> 6,  dd = ncol & 63;      // dd = head dim
                bf16_t v = (bf16_t)acc[m][n][r];
                unsigned head = (unsigned)(bb * 16 + hh) << 16;   // *65536
                if (wsel == 0) {
                    unsigned idx = (unsigned)(((ss >> 5) * 4 + (dd >> 4)) * 512
                                 + ((dd >> 3) & 1) * 256 + (ss & 31) * 8 + (dd & 7));
                    q[head + idx] = v;
                } else if (wsel == 1) {
                    unsigned idx = (unsigned)(((ss >> 6) * 8 + (dd >> 4) * 2 + ((ss >> 5) & 1)) * 512
                                 + ((dd >> 3) & 1) * 256 + (ss & 31) * 8 + (dd & 7));
                    k[head + idx] = v;
                } else {
                    unsigned idx = (unsigned)(((ss >> 6) * 8 + ((ss >> 4) & 3) * 2 + (dd >> 5)) * 512
                                 + ((ss >> 3) & 1) * 256 + (dd & 31) * 8 + (ss & 7));
                    vt[head + idx] = v;
                }
            }
        }
    }
}

// ---------------- flash attention (unchanged, passing) ----------------
__global__ __launch_bounds__(256) void attn_kernel(const bf16_t* __restrict__ Q,
                                                   const bf16_t* __restrict__ K,
                                                   const bf16_t* __restrict__ Vt,
                                                   float* __restrict__ out) {
    __shared__ float olds[4 * 64 * 33];
    const int w = threadIdx.x >> 6, l = threadIdx.x & 63;
    const int hb = blockIdx.x & 127;
    const int qblk = blockIdx.x >> 7;
    const int qw = qblk * 4 + w;
    const int b = hb >> 4, h = hb & 15;
    const int ln = l & 31, hi = l >> 5;
    const unsigned bh = (unsigned)hb << 16;
    const bf16_t* Qh = Q + bh;
    const bf16_t* Kh = K + bh;
    const bf16_t* Vh = Vt + bh;
    const int l8 = l * 8;

    bf16x8 qf[4];
#pragma unroll
    for (int s = 0; s < 4; ++s)
        qf[s] = *(const bf16x8*)&Qh[(qw * 4 + s) * 512 + l8];

    f32x16 of0, of1;
#pragma unroll
    for (int r = 0; r < 16; ++r) { of0[r] = 0.f; of1[r] = 0.f; }
    float lsum = 0.f;

    for (int kt = 0; kt < 16; ++kt) {
        const bf16_t* Kt = Kh + kt * 4096;
        const bf16_t* Vtt = Vh + kt * 4096;
        f32x16 sc0, sc1;
#pragma unroll
        for (int r = 0; r < 16; ++r) { sc0[r] = 0.f; sc1[r] = 0.f; }
        __builtin_amdgcn_s_setprio(1);
#pragma unroll
        for (int s = 0; s < 4; ++s) {
            bf16x8 k0 = *(const bf16x8*)&Kt[(s * 2 + 0) * 512 + l8];
            bf16x8 k1 = *(const bf16x8*)&Kt[(s * 2 + 1) * 512 + l8];
            sc0 = MFMA32(k0, qf[s], sc0);
            sc1 = MFMA32(k1, qf[s], sc1);
        }
        __builtin_amdgcn_s_setprio(0);
        bf16x8 vf0[4], vf1[4];
#pragma unroll
        for (int S = 0; S < 4; ++S) {
            vf0[S] = *(const bf16x8*)&Vtt[(S * 2 + 0) * 512 + l8];
            vf1[S] = *(const bf16x8*)&Vtt[(S * 2 + 1) * 512 + l8];
        }
        float p0[16], p1[16];
#pragma unroll
        for (int r = 0; r < 16; ++r) {
            p0[r] = __builtin_amdgcn_exp2f(sc0[r]);
            p1[r] = __builtin_amdgcn_exp2f(sc1[r]);
        }
        float s_[16];
#pragma unroll
        for (int r = 0; r < 16; ++r) s_[r] = p0[r] + p1[r];
#pragma unroll
        for (int st = 8; st >= 1; st >>= 1)
#pragma unroll
            for (int r = 0; r < 8; ++r)
                if (r < st) s_[r] += s_[r + st];
        lsum += s_[0];
        unsigned own[16];
#pragma unroll
        for (int t = 0; t < 8; ++t) {
            bf16x2 v0; v0[0] = (bf16_t)p0[2 * t]; v0[1] = (bf16_t)p0[2 * t + 1];
            bf16x2 v1; v1[0] = (bf16_t)p1[2 * t]; v1[1] = (bf16_t)p1[2 * t + 1];
            own[t]     = __builtin_bit_cast(unsigned, v0);
            own[8 + t] = __builtin_bit_cast(unsigned, v1);
        }
        __builtin_amdgcn_s_setprio(1);
#pragma unroll
        for (int S = 0; S < 4; ++S) {
            const int b0 = (S >> 1) * 8 + (S & 1) * 4;
            unsigned w0 = own[b0 + 0], w2 = own[b0 + 2];
            unsigned w1 = own[b0 + 1], w3 = own[b0 + 3];
            asm("v_permlane32_swap_b32 %0, %1" : "+v"(w0), "+v"(w2));
            asm("v_permlane32_swap_b32 %0, %1" : "+v"(w1), "+v"(w3));
            union { unsigned u[4]; bf16x8 v; } pb;
            pb.u[0] = w0; pb.u[1] = w1; pb.u[2] = w2; pb.u[3] = w3;
            of0 = MFMA32(vf0[S], pb.v, of0);
            of1 = MFMA32(vf1[S], pb.v, of1);
        }
        __builtin_amdgcn_s_setprio(0);
    }

    float ltot = lsum + __shfl_xor(lsum, 32);
    float inv = 1.f / ltot;
    float* ol = olds + w * (64 * 33);
#pragma unroll
    for (int r = 0; r < 16; ++r) {
        int d = (r & 3) + 8 * (r >> 2) + 4 * hi;
        ol[d * 33 + ln]        = of0[r] * inv;
        ol[(32 + d) * 33 + ln] = of1[r] * inv;
    }
    const unsigned obase = (unsigned)(b * 1024 + qw * 32) * 1024u + h * 64 + l;
#pragma unroll 8
    for (int qq = 0; qq < 32; ++qq)
        out[obase + qq * 1024u] = ol[l * 33 + qq];
}

extern "C" void kernel_launch(void* const* d_in, const int* in_sizes, int n_in,
                              void* d_out, int out_size, void* d_ws, size_t ws_size,
                              hipStream_t stream) {
    const float* x  = (const float*)d_in[0];
    const float* qw = (const float*)d_in[1];
    const float* kw = (const float*)d_in[2];
    const float* vw = (const float*)d_in[3];
    float* out = (float*)d_out;
    char* ws = (char*)d_ws;
    if (ws_size < 67633152u) return;

    bf16_t* xf = (bf16_t*)(ws + XB_OFF);
    bf16_t* wf = (bf16_t*)(ws + WT_OFF);
    bf16_t* Qb = (bf16_t*)(ws + Q_OFF);
    bf16_t* Kb = (bf16_t*)(ws + K_OFF);
    bf16_t* Vt = (bf16_t*)(ws + VT_OFF);

    cast_kernel<<<8448, 256, 0, stream>>>((const float4*)x, xf, qw, kw, vw, wf);
    proj_kernel<<<1536, 256, 0, stream>>>(xf, wf, Qb, Kb, Vt);
    attn_kernel<<<1024, 256, 0, stream>>>(Qb, Kb, Vt, out);
}

// Round 10
// 135.110 us; speedup vs baseline: 1.0754x; 1.0754x over previous
//
#include <hip/hip_runtime.h>

typedef __bf16 bf16_t;
typedef __attribute__((ext_vector_type(2))) __bf16 bf16x2;
typedef __attribute__((ext_vector_type(4))) __bf16 bf16x4;
typedef __attribute__((ext_vector_type(8))) __bf16 bf16x8;
typedef __attribute__((ext_vector_type(4))) float f32x4;
typedef __attribute__((ext_vector_type(16))) float f32x16;

#define MFMA16(a, b, c) __builtin_amdgcn_mfma_f32_16x16x32_bf16((a), (b), (c), 0, 0, 0)
#define MFMA32(a, b, c) __builtin_amdgcn_mfma_f32_32x32x16_bf16((a), (b), (c), 0, 0, 0)
#define AS1 __attribute__((address_space(1)))
#define AS3 __attribute__((address_space(3)))

// Problem: B=8 S=1024 D=768 H=16 Dh=64 OD=1024, M = B*S = 8192
static constexpr unsigned XB_OFF = 0u;                          // x bf16 row-major: 12,582,912
static constexpr unsigned WT_OFF = 12582912u;                   // wT bf16 (3,1024,768): 4,718,592
static constexpr unsigned Q_OFF  = WT_OFF + 4718592u;           // Qf bf16: 16,777,216
static constexpr unsigned K_OFF  = Q_OFF + 16777216u;
static constexpr unsigned VT_OFF = K_OFF + 16777216u;           // end = 67,633,152

// ---------------- merged cast kernel (row-major outputs, as in r8) ----------
__global__ __launch_bounds__(256) void cast_kernel(const float4* __restrict__ x4,
                                                   bf16x4* __restrict__ out4,
                                                   const float* __restrict__ qw,
                                                   const float* __restrict__ kw,
                                                   const float* __restrict__ vw,
                                                   bf16_t* __restrict__ wT) {
    if (blockIdx.x < 6144u) {
        unsigned i = blockIdx.x * 256u + threadIdx.x;
        float4 v = x4[i];
        bf16x4 o;
        o[0] = (bf16_t)v.x; o[1] = (bf16_t)v.y; o[2] = (bf16_t)v.z; o[3] = (bf16_t)v.w;
        out4[i] = o;
    } else {
        unsigned t = (blockIdx.x - 6144u) * 256u + threadIdx.x;
        unsigned w  = t / 196608u;
        unsigned r  = t % 196608u;
        unsigned n  = r % 1024u;
        unsigned k4 = r / 1024u;
        const float* src = (w == 0u) ? qw : (w == 1u) ? kw : vw;
        float s = (w == 0u) ? 0.18033688011112043f : 1.0f;   // 0.125*log2(e) folded for exp2
        bf16x4 o;
#pragma unroll
        for (int i = 0; i < 4; ++i) o[i] = (bf16_t)(src[(k4 * 4u + i) * 1024u + n] * s);
        *(bf16x4*)&wT[(w * 1024u + n) * 768u + k4 * 4u] = o;
    }
}

// ---------------- fused QKV projection GEMM, counted-vmcnt pipeline ----------
// BM=BN=128, 4 waves (256 thr, 2x2 of 64x64). 24 phases of K=32. 4 LDS slots
// (64KB total -> 2 blocks/CU: barrier/vmcnt waits of one block hide under the
// other block's compute). r8's verified ledger rescaled: 4 loads/stage,
// prologue vmcnt(8), steady vmcnt(8) (2 slots pending), tail vmcnt(4)/(0).
// XOR granule swizzle identical to r7/r8 (verified 0 conflicts).
__global__ __launch_bounds__(256, 2) void proj_kernel(const bf16_t* __restrict__ xb,
                                                      const bf16_t* __restrict__ wT,
                                                      bf16_t* __restrict__ q,
                                                      bf16_t* __restrict__ k,
                                                      bf16_t* __restrict__ vt) {
    __shared__ __align__(16) bf16_t As[4][128 * 32];
    __shared__ __align__(16) bf16_t Bs[4][128 * 32];
    const int id = blockIdx.x;
    const int work = (id & 7) * 192 + (id >> 3);        // bijective, 1536 = 8*192
    const int nb = work & 7, mb = (work >> 3) & 63, wsel = work >> 9;
    const int t = threadIdx.x;
    const int w = t >> 6, l = t & 63;
    const int lo = l & 15, hi = l >> 4;
    const int wm = w >> 1, wn = w & 1;                  // 2x2 waves, 64x64 each
    const bf16_t* abase = xb + mb * 128 * 768;
    const bf16_t* bbase = wT + wsel * (1024 * 768) + nb * 128 * 768;
    // staging: thread covers row i*64 + w*16 + (l>>2), granule l&3 (16B);
    // source granule pre-swizzled (l&3)^((l>>3)&3); (row>>1)&3 == (l>>3)&3.
    const int srow = w * 16 + (l >> 2);
    const int gsrc = ((l & 3) ^ ((l >> 3) & 3)) * 8;
    const int rg = (hi ^ ((lo >> 1) & 3)) << 3;         // read-side granule

#define STAGE(slot, p)                                                              \
    do {                                                                            \
        const int ko_ = (p) * 32 + gsrc;                                            \
        __builtin_amdgcn_global_load_lds((const AS1 void*)(abase + srow * 768 + ko_),       \
                                         (AS3 void*)(&As[slot][w * 512]), 16, 0, 0);        \
        __builtin_amdgcn_global_load_lds((const AS1 void*)(abase + (64 + srow) * 768 + ko_),\
                                         (AS3 void*)(&As[slot][2048 + w * 512]), 16, 0, 0); \
        __builtin_amdgcn_global_load_lds((const AS1 void*)(bbase + srow * 768 + ko_),       \
                                         (AS3 void*)(&Bs[slot][w * 512]), 16, 0, 0);        \
        __builtin_amdgcn_global_load_lds((const AS1 void*)(bbase + (64 + srow) * 768 + ko_),\
                                         (AS3 void*)(&Bs[slot][2048 + w * 512]), 16, 0, 0); \
    } while (0)

    bf16x8 af[4], bfr[4];
#define DSREAD(slotv)                                                             \
    do {                                                                          \
        const bf16_t* Ab_ = As[slotv];                                            \
        const bf16_t* Bb_ = Bs[slotv];                                            \
        _Pragma("unroll") for (int m_ = 0; m_ < 4; ++m_)                          \
            af[m_] = *(const bf16x8*)&Ab_[(wm * 64 + m_ * 16 + lo) * 32 + rg];    \
        _Pragma("unroll") for (int n_ = 0; n_ < 4; ++n_)                          \
            bfr[n_] = *(const bf16x8*)&Bb_[(wn * 64 + n_ * 16 + lo) * 32 + rg];   \
    } while (0)

#define DOMFMA()                                                                  \
    do {                                                                          \
        __builtin_amdgcn_s_setprio(1);                                            \
        _Pragma("unroll") for (int m_ = 0; m_ < 4; ++m_)                          \
        _Pragma("unroll") for (int n_ = 0; n_ < 4; ++n_)                          \
            acc[m_][n_] = MFMA16(af[m_], bfr[n_], acc[m_][n_]);                   \
        __builtin_amdgcn_s_setprio(0);                                            \
    } while (0)

    f32x4 acc[4][4];
#pragma unroll
    for (int m = 0; m < 4; ++m)
#pragma unroll
        for (int n = 0; n < 4; ++n)
#pragma unroll
            for (int i = 0; i < 4; ++i) acc[m][n][i] = 0.f;

    // prologue: 3 slots in flight (12 loads), publish slot 0
    STAGE(0, 0);
    STAGE(1, 1);
    STAGE(2, 2);
    asm volatile("s_waitcnt vmcnt(8)" ::: "memory");
    __builtin_amdgcn_s_barrier();

    for (int p = 0; p < 21; ++p) {
        const int slot = p & 3;
        DSREAD(slot);                     // slot p published by previous barrier
        STAGE((p + 3) & 3, p + 3);        // targets slot p-1: reads retired last iter
        asm volatile("s_waitcnt vmcnt(8)" ::: "memory");   // slot p+1 complete
        __builtin_amdgcn_s_barrier();     // publish slot p+1
        DOMFMA();
        asm volatile("s_waitcnt lgkmcnt(0)" ::: "memory"); // my reads of slot p done
        __builtin_amdgcn_s_barrier();     // slot p now safe to overwrite
    }
    // tail: p = 21, 22, 23 (no more stages; counted drain 8 -> 4 -> 0)
    DSREAD(1);
    asm volatile("s_waitcnt vmcnt(4)" ::: "memory");
    __builtin_amdgcn_s_barrier();
    DOMFMA();
    asm volatile("s_waitcnt lgkmcnt(0)" ::: "memory");
    __builtin_amdgcn_s_barrier();
    DSREAD(2);
    asm volatile("s_waitcnt vmcnt(0)" ::: "memory");
    __builtin_amdgcn_s_barrier();
    DOMFMA();
    asm volatile("s_waitcnt lgkmcnt(0)" ::: "memory");
    __builtin_amdgcn_s_barrier();
    DSREAD(3);
    DOMFMA();
#undef STAGE
#undef DSREAD
#undef DOMFMA

    // epilogue: scatter to fragment-order Qf/Kf/Vf layouts (unchanged math)
    const int rbase = mb * 128 + wm * 64;
    const int cbase = nb * 128 + wn * 64;
#pragma unroll
    for (int m = 0; m < 4; ++m) {
#pragma unroll
        for (int n = 0; n < 4; ++n) {
#pragma unroll
            for (int r = 0; r < 4; ++r) {
                int mrow = rbase + m * 16 + hi * 4 + r;   // C/D: row=(l>>4)*4+r
                int ncol = cbase + n * 16 + lo;           //      col=l&15
                int bb = mrow >> 10, ss = mrow & 1023;    // ss = seq pos
                int hh = ncol >> 6,  dd = ncol & 63;      // dd = head dim
                bf16_t v = (bf16_t)acc[m][n][r];
                unsigned head = (unsigned)(bb * 16 + hh) << 16;   // *65536
                if (wsel == 0) {
                    unsigned idx = (unsigned)(((ss >> 5) * 4 + (dd >> 4)) * 512
                                 + ((dd >> 3) & 1) * 256 + (ss & 31) * 8 + (dd & 7));
                    q[head + idx] = v;
                } else if (wsel == 1) {
                    unsigned idx = (unsigned)(((ss >> 6) * 8 + (dd >> 4) * 2 + ((ss >> 5) & 1)) * 512
                                 + ((dd >> 3) & 1) * 256 + (ss & 31) * 8 + (dd & 7));
                    k[head + idx] = v;
                } else {
                    unsigned idx = (unsigned)(((ss >> 6) * 8 + ((ss >> 4) & 3) * 2 + (dd >> 5)) * 512
                                 + ((ss >> 3) & 1) * 256 + (dd & 31) * 8 + (ss & 7));
                    vt[head + idx] = v;
                }
            }
        }
    }
}

// ---------------- flash attention (unchanged, passing) ----------------
__global__ __launch_bounds__(256) void attn_kernel(const bf16_t* __restrict__ Q,
                                                   const bf16_t* __restrict__ K,
                                                   const bf16_t* __restrict__ Vt,
                                                   float* __restrict__ out) {
    __shared__ float olds[4 * 64 * 33];
    const int w = threadIdx.x >> 6, l = threadIdx.x & 63;
    const int hb = blockIdx.x & 127;
    const int qblk = blockIdx.x >> 7;
    const int qw = qblk * 4 + w;
    const int b = hb >> 4, h = hb & 15;
    const int ln = l & 31, hi = l >> 5;
    const unsigned bh = (unsigned)hb << 16;
    const bf16_t* Qh = Q + bh;
    const bf16_t* Kh = K + bh;
    const bf16_t* Vh = Vt + bh;
    const int l8 = l * 8;

    bf16x8 qf[4];
#pragma unroll
    for (int s = 0; s < 4; ++s)
        qf[s] = *(const bf16x8*)&Qh[(qw * 4 + s) * 512 + l8];

    f32x16 of0, of1;
#pragma unroll
    for (int r = 0; r < 16; ++r) { of0[r] = 0.f; of1[r] = 0.f; }
    float lsum = 0.f;

    for (int kt = 0; kt < 16; ++kt) {
        const bf16_t* Kt = Kh + kt * 4096;
        const bf16_t* Vtt = Vh + kt * 4096;
        f32x16 sc0, sc1;
#pragma unroll
        for (int r = 0; r < 16; ++r) { sc0[r] = 0.f; sc1[r] = 0.f; }
        __builtin_amdgcn_s_setprio(1);
#pragma unroll
        for (int s = 0; s < 4; ++s) {
            bf16x8 k0 = *(const bf16x8*)&Kt[(s * 2 + 0) * 512 + l8];
            bf16x8 k1 = *(const bf16x8*)&Kt[(s * 2 + 1) * 512 + l8];
            sc0 = MFMA32(k0, qf[s], sc0);
            sc1 = MFMA32(k1, qf[s], sc1);
        }
        __builtin_amdgcn_s_setprio(0);
        bf16x8 vf0[4], vf1[4];
#pragma unroll
        for (int S = 0; S < 4; ++S) {
            vf0[S] = *(const bf16x8*)&Vtt[(S * 2 + 0) * 512 + l8];
            vf1[S] = *(const bf16x8*)&Vtt[(S * 2 + 1) * 512 + l8];
        }
        float p0[16], p1[16];
#pragma unroll
        for (int r = 0; r < 16; ++r) {
            p0[r] = __builtin_amdgcn_exp2f(sc0[r]);
            p1[r] = __builtin_amdgcn_exp2f(sc1[r]);
        }
        float s_[16];
#pragma unroll
        for (int r = 0; r < 16; ++r) s_[r] = p0[r] + p1[r];
#pragma unroll
        for (int st = 8; st >= 1; st >>= 1)
#pragma unroll
            for (int r = 0; r < 8; ++r)
                if (r < st) s_[r] += s_[r + st];
        lsum += s_[0];
        unsigned own[16];
#pragma unroll
        for (int t = 0; t < 8; ++t) {
            bf16x2 v0; v0[0] = (bf16_t)p0[2 * t]; v0[1] = (bf16_t)p0[2 * t + 1];
            bf16x2 v1; v1[0] = (bf16_t)p1[2 * t]; v1[1] = (bf16_t)p1[2 * t + 1];
            own[t]     = __builtin_bit_cast(unsigned, v0);
            own[8 + t] = __builtin_bit_cast(unsigned, v1);
        }
        __builtin_amdgcn_s_setprio(1);
#pragma unroll
        for (int S = 0; S < 4; ++S) {
            const int b0 = (S >> 1) * 8 + (S & 1) * 4;
            unsigned w0 = own[b0 + 0], w2 = own[b0 + 2];
            unsigned w1 = own[b0 + 1], w3 = own[b0 + 3];
            asm("v_permlane32_swap_b32 %0, %1" : "+v"(w0), "+v"(w2));
            asm("v_permlane32_swap_b32 %0, %1" : "+v"(w1), "+v"(w3));
            union { unsigned u[4]; bf16x8 v; } pb;
            pb.u[0] = w0; pb.u[1] = w1; pb.u[2] = w2; pb.u[3] = w3;
            of0 = MFMA32(vf0[S], pb.v, of0);
            of1 = MFMA32(vf1[S], pb.v, of1);
        }
        __builtin_amdgcn_s_setprio(0);
    }

    float ltot = lsum + __shfl_xor(lsum, 32);
    float inv = 1.f / ltot;
    float* ol = olds + w * (64 * 33);
#pragma unroll
    for (int r = 0; r < 16; ++r) {
        int d = (r & 3) + 8 * (r >> 2) + 4 * hi;
        ol[d * 33 + ln]        = of0[r] * inv;
        ol[(32 + d) * 33 + ln] = of1[r] * inv;
    }
    const unsigned obase = (unsigned)(b * 1024 + qw * 32) * 1024u + h * 64 + l;
#pragma unroll 8
    for (int qq = 0; qq < 32; ++qq)
        out[obase + qq * 1024u] = ol[l * 33 + qq];
}

extern "C" void kernel_launch(void* const* d_in, const int* in_sizes, int n_in,
                              void* d_out, int out_size, void* d_ws, size_t ws_size,
                              hipStream_t stream) {
    const float* x  = (const float*)d_in[0];
    const float* qw = (const float*)d_in[1];
    const float* kw = (const float*)d_in[2];
    const float* vw = (const float*)d_in[3];
    float* out = (float*)d_out;
    char* ws = (char*)d_ws;
    if (ws_size < 67633152u) return;

    bf16_t* xb = (bf16_t*)(ws + XB_OFF);
    bf16_t* wT = (bf16_t*)(ws + WT_OFF);
    bf16_t* Qb = (bf16_t*)(ws + Q_OFF);
    bf16_t* Kb = (bf16_t*)(ws + K_OFF);
    bf16_t* Vt = (bf16_t*)(ws + VT_OFF);

    cast_kernel<<<8448, 256, 0, stream>>>((const float4*)x, (bf16x4*)xb, qw, kw, vw, wT);
    proj_kernel<<<1536, 256, 0, stream>>>(xb, wT, Qb, Kb, Vt);
    attn_kernel<<<1024, 256, 0, stream>>>(Qb, Kb, Vt, out);
}

// Round 11
// 127.855 us; speedup vs baseline: 1.1364x; 1.0567x over previous
//
#include <hip/hip_runtime.h>

typedef __bf16 bf16_t;
typedef __attribute__((ext_vector_type(2))) __bf16 bf16x2;
typedef __attribute__((ext_vector_type(4))) __bf16 bf16x4;
typedef __attribute__((ext_vector_type(8))) __bf16 bf16x8;
typedef __attribute__((ext_vector_type(4))) float f32x4;
typedef __attribute__((ext_vector_type(16))) float f32x16;

#define MFMA16(a, b, c) __builtin_amdgcn_mfma_f32_16x16x32_bf16((a), (b), (c), 0, 0, 0)
#define MFMA32(a, b, c) __builtin_amdgcn_mfma_f32_32x32x16_bf16((a), (b), (c), 0, 0, 0)
#define AS1 __attribute__((address_space(1)))
#define AS3 __attribute__((address_space(3)))

// Problem: B=8 S=1024 D=768 H=16 Dh=64 OD=1024, M = B*S = 8192
static constexpr unsigned XB_OFF = 0u;                          // x bf16 row-major: 12,582,912
static constexpr unsigned WT_OFF = 12582912u;                   // wT bf16 (3,1024,768): 4,718,592
static constexpr unsigned Q_OFF  = WT_OFF + 4718592u;           // Qf bf16: 16,777,216
static constexpr unsigned K_OFF  = Q_OFF + 16777216u;
static constexpr unsigned VT_OFF = K_OFF + 16777216u;           // end = 67,633,152

// ---------------- merged cast kernel ----------------
__global__ __launch_bounds__(256) void cast_kernel(const float4* __restrict__ x4,
                                                   bf16x4* __restrict__ out4,
                                                   const float* __restrict__ qw,
                                                   const float* __restrict__ kw,
                                                   const float* __restrict__ vw,
                                                   bf16_t* __restrict__ wT) {
    if (blockIdx.x < 6144u) {
        unsigned i = blockIdx.x * 256u + threadIdx.x;
        float4 v = x4[i];
        bf16x4 o;
        o[0] = (bf16_t)v.x; o[1] = (bf16_t)v.y; o[2] = (bf16_t)v.z; o[3] = (bf16_t)v.w;
        out4[i] = o;
    } else {
        unsigned t = (blockIdx.x - 6144u) * 256u + threadIdx.x;
        unsigned w  = t / 196608u;
        unsigned r  = t % 196608u;
        unsigned n  = r % 1024u;
        unsigned k4 = r / 1024u;
        const float* src = (w == 0u) ? qw : (w == 1u) ? kw : vw;
        float s = (w == 0u) ? 0.18033688011112043f : 1.0f;   // 0.125*log2(e) folded for exp2
        bf16x4 o;
#pragma unroll
        for (int i = 0; i < 4; ++i) o[i] = (bf16_t)(src[(k4 * 4u + i) * 1024u + n] * s);
        *(bf16x4*)&wT[(w * 1024u + n) * 768u + k4 * 4u] = o;
    }
}

// ---------------- fused QKV projection GEMM, high-density phases -------------
// BM=256 BN=128, 4 waves (2Mx2N), per-wave output 128x64 -> 32 MFMA/phase
// (2x the MFMA density of the r7-r10 structures; that ratio was the ceiling).
// 24 phases of K=32. 3 LDS slots x 24KB = 72KB -> 2 blocks/CU. Counted-vmcnt
// ledger: 6 loads/stage, 2 stages in flight, steady vmcnt(6), tail vmcnt(0).
// Stage at phase p targets slot consumed at p-1 (retired by lgkmcnt(0)+barrier).
// XOR granule swizzle identical to r7-r10 (verified 0 conflicts).
__global__ __launch_bounds__(256, 2) void proj_kernel(const bf16_t* __restrict__ xb,
                                                      const bf16_t* __restrict__ wT,
                                                      bf16_t* __restrict__ q,
                                                      bf16_t* __restrict__ k,
                                                      bf16_t* __restrict__ vt) {
    __shared__ __align__(16) bf16_t As[3][256 * 32];
    __shared__ __align__(16) bf16_t Bs[3][128 * 32];
    const int id = blockIdx.x;
    const int work = (id & 7) * 96 + (id >> 3);        // bijective, 768 = 8*96
    const int nb = work & 7, mb = (work >> 3) & 31, wsel = work >> 8;
    const int t = threadIdx.x;
    const int w = t >> 6, l = t & 63;
    const int lo = l & 15, hi = l >> 4;
    const int wm = w >> 1, wn = w & 1;                  // 2x2 waves; per-wave 128x64
    const bf16_t* abase = xb + mb * 256 * 768;
    const bf16_t* bbase = wT + wsel * (1024 * 768) + nb * 128 * 768;
    // staging row within 64-row group: w*16 + (l>>2); granule l&3 (16B);
    // source granule pre-swizzled (l&3)^((l>>3)&3); (row>>1)&3 == (l>>3)&3.
    const int srow = w * 16 + (l >> 2);
    const int gsrc = ((l & 3) ^ ((l >> 3) & 3)) * 8;
    const int rg = (hi ^ ((lo >> 1) & 3)) << 3;         // read-side granule

#define STAGE(slot, p)                                                              \
    do {                                                                            \
        const int ko_ = (p) * 32 + gsrc;                                            \
        _Pragma("unroll")                                                           \
        for (int g_ = 0; g_ < 4; ++g_)                                              \
            __builtin_amdgcn_global_load_lds(                                       \
                (const AS1 void*)(abase + (g_ * 64 + srow) * 768 + ko_),            \
                (AS3 void*)(&As[slot][g_ * 2048 + w * 512]), 16, 0, 0);             \
        _Pragma("unroll")                                                           \
        for (int g_ = 0; g_ < 2; ++g_)                                              \
            __builtin_amdgcn_global_load_lds(                                       \
                (const AS1 void*)(bbase + (g_ * 64 + srow) * 768 + ko_),            \
                (AS3 void*)(&Bs[slot][g_ * 2048 + w * 512]), 16, 0, 0);             \
    } while (0)

    bf16x8 af[8], bfr[4];
#define DSREAD(slotv)                                                             \
    do {                                                                          \
        const bf16_t* Ab_ = As[slotv];                                            \
        const bf16_t* Bb_ = Bs[slotv];                                            \
        _Pragma("unroll") for (int m_ = 0; m_ < 8; ++m_)                          \
            af[m_] = *(const bf16x8*)&Ab_[(wm * 128 + m_ * 16 + lo) * 32 + rg];   \
        _Pragma("unroll") for (int n_ = 0; n_ < 4; ++n_)                          \
            bfr[n_] = *(const bf16x8*)&Bb_[(wn * 64 + n_ * 16 + lo) * 32 + rg];   \
    } while (0)

#define DOMFMA()                                                                  \
    do {                                                                          \
        __builtin_amdgcn_s_setprio(1);                                            \
        _Pragma("unroll") for (int m_ = 0; m_ < 8; ++m_)                          \
        _Pragma("unroll") for (int n_ = 0; n_ < 4; ++n_)                          \
            acc[m_][n_] = MFMA16(af[m_], bfr[n_], acc[m_][n_]);                   \
        __builtin_amdgcn_s_setprio(0);                                            \
    } while (0)

    f32x4 acc[8][4];
#pragma unroll
    for (int m = 0; m < 8; ++m)
#pragma unroll
        for (int n = 0; n < 4; ++n)
#pragma unroll
            for (int i = 0; i < 4; ++i) acc[m][n][i] = 0.f;

    // prologue: 2 slots in flight (12 loads), publish slot 0
    STAGE(0, 0);
    STAGE(1, 1);
    asm volatile("s_waitcnt vmcnt(6)" ::: "memory");
    __builtin_amdgcn_s_barrier();

    int slot = 0;
    for (int p = 0; p < 22; ++p) {
        DSREAD(slot);                        // slot p published by previous barrier
        const int s2 = (slot + 2 >= 3) ? slot - 1 : slot + 2;
        STAGE(s2, p + 2);                    // targets slot p-1: reads retired last iter
        asm volatile("s_waitcnt vmcnt(6)" ::: "memory");   // slot p+1 complete
        __builtin_amdgcn_s_barrier();        // publish slot p+1
        DOMFMA();
        asm volatile("s_waitcnt lgkmcnt(0)" ::: "memory"); // my reads of slot p done
        __builtin_amdgcn_s_barrier();        // slot p now safe to overwrite
        slot = (slot + 1 >= 3) ? 0 : slot + 1;
    }
    // tail: p = 22, 23 (no more stages; drain to 0)
    DSREAD(1);                               // 22 % 3
    asm volatile("s_waitcnt vmcnt(0)" ::: "memory");
    __builtin_amdgcn_s_barrier();
    DOMFMA();
    asm volatile("s_waitcnt lgkmcnt(0)" ::: "memory");
    __builtin_amdgcn_s_barrier();
    DSREAD(2);                               // 23 % 3
    DOMFMA();
#undef STAGE
#undef DSREAD
#undef DOMFMA

    // epilogue: scatter to fragment-order Qf/Kf/Vf layouts (unchanged math)
    const int rbase = mb * 256 + wm * 128;
    const int cbase = nb * 128 + wn * 64;
#pragma unroll
    for (int m = 0; m < 8; ++m) {
#pragma unroll
        for (int n = 0; n < 4; ++n) {
#pragma unroll
            for (int r = 0; r < 4; ++r) {
                int mrow = rbase + m * 16 + hi * 4 + r;   // C/D: row=(l>>4)*4+r
                int ncol = cbase + n * 16 + lo;           //      col=l&15
                int bb = mrow >> 10, ss = mrow & 1023;    // ss = seq pos
                int hh = ncol >> 6,  dd = ncol & 63;      // dd = head dim
                bf16_t v = (bf16_t)acc[m][n][r];
                unsigned head = (unsigned)(bb * 16 + hh) << 16;   // *65536
                if (wsel == 0) {
                    unsigned idx = (unsigned)(((ss >> 5) * 4 + (dd >> 4)) * 512
                                 + ((dd >> 3) & 1) * 256 + (ss & 31) * 8 + (dd & 7));
                    q[head + idx] = v;
                } else if (wsel == 1) {
                    unsigned idx = (unsigned)(((ss >> 6) * 8 + (dd >> 4) * 2 + ((ss >> 5) & 1)) * 512
                                 + ((dd >> 3) & 1) * 256 + (ss & 31) * 8 + (dd & 7));
                    k[head + idx] = v;
                } else {
                    unsigned idx = (unsigned)(((ss >> 6) * 8 + ((ss >> 4) & 3) * 2 + (dd >> 5)) * 512
                                 + ((ss >> 3) & 1) * 256 + (dd & 31) * 8 + (ss & 7));
                    vt[head + idx] = v;
                }
            }
        }
    }
}

// ---------------- flash attention (unchanged, passing) ----------------
__global__ __launch_bounds__(256) void attn_kernel(const bf16_t* __restrict__ Q,
                                                   const bf16_t* __restrict__ K,
                                                   const bf16_t* __restrict__ Vt,
                                                   float* __restrict__ out) {
    __shared__ float olds[4 * 64 * 33];
    const int w = threadIdx.x >> 6, l = threadIdx.x & 63;
    const int hb = blockIdx.x & 127;
    const int qblk = blockIdx.x >> 7;
    const int qw = qblk * 4 + w;
    const int b = hb >> 4, h = hb & 15;
    const int ln = l & 31, hi = l >> 5;
    const unsigned bh = (unsigned)hb << 16;
    const bf16_t* Qh = Q + bh;
    const bf16_t* Kh = K + bh;
    const bf16_t* Vh = Vt + bh;
    const int l8 = l * 8;

    bf16x8 qf[4];
#pragma unroll
    for (int s = 0; s < 4; ++s)
        qf[s] = *(const bf16x8*)&Qh[(qw * 4 + s) * 512 + l8];

    f32x16 of0, of1;
#pragma unroll
    for (int r = 0; r < 16; ++r) { of0[r] = 0.f; of1[r] = 0.f; }
    float lsum = 0.f;

    for (int kt = 0; kt < 16; ++kt) {
        const bf16_t* Kt = Kh + kt * 4096;
        const bf16_t* Vtt = Vh + kt * 4096;
        f32x16 sc0, sc1;
#pragma unroll
        for (int r = 0; r < 16; ++r) { sc0[r] = 0.f; sc1[r] = 0.f; }
        __builtin_amdgcn_s_setprio(1);
#pragma unroll
        for (int s = 0; s < 4; ++s) {
            bf16x8 k0 = *(const bf16x8*)&Kt[(s * 2 + 0) * 512 + l8];
            bf16x8 k1 = *(const bf16x8*)&Kt[(s * 2 + 1) * 512 + l8];
            sc0 = MFMA32(k0, qf[s], sc0);
            sc1 = MFMA32(k1, qf[s], sc1);
        }
        __builtin_amdgcn_s_setprio(0);
        bf16x8 vf0[4], vf1[4];
#pragma unroll
        for (int S = 0; S < 4; ++S) {
            vf0[S] = *(const bf16x8*)&Vtt[(S * 2 + 0) * 512 + l8];
            vf1[S] = *(const bf16x8*)&Vtt[(S * 2 + 1) * 512 + l8];
        }
        float p0[16], p1[16];
#pragma unroll
        for (int r = 0; r < 16; ++r) {
            p0[r] = __builtin_amdgcn_exp2f(sc0[r]);
            p1[r] = __builtin_amdgcn_exp2f(sc1[r]);
        }
        float s_[16];
#pragma unroll
        for (int r = 0; r < 16; ++r) s_[r] = p0[r] + p1[r];
#pragma unroll
        for (int st = 8; st >= 1; st >>= 1)
#pragma unroll
            for (int r = 0; r < 8; ++r)
                if (r < st) s_[r] += s_[r + st];
        lsum += s_[0];
        unsigned own[16];
#pragma unroll
        for (int t = 0; t < 8; ++t) {
            bf16x2 v0; v0[0] = (bf16_t)p0[2 * t]; v0[1] = (bf16_t)p0[2 * t + 1];
            bf16x2 v1; v1[0] = (bf16_t)p1[2 * t]; v1[1] = (bf16_t)p1[2 * t + 1];
            own[t]     = __builtin_bit_cast(unsigned, v0);
            own[8 + t] = __builtin_bit_cast(unsigned, v1);
        }
        __builtin_amdgcn_s_setprio(1);
#pragma unroll
        for (int S = 0; S < 4; ++S) {
            const int b0 = (S >> 1) * 8 + (S & 1) * 4;
            unsigned w0 = own[b0 + 0], w2 = own[b0 + 2];
            unsigned w1 = own[b0 + 1], w3 = own[b0 + 3];
            asm("v_permlane32_swap_b32 %0, %1" : "+v"(w0), "+v"(w2));
            asm("v_permlane32_swap_b32 %0, %1" : "+v"(w1), "+v"(w3));
            union { unsigned u[4]; bf16x8 v; } pb;
            pb.u[0] = w0; pb.u[1] = w1; pb.u[2] = w2; pb.u[3] = w3;
            of0 = MFMA32(vf0[S], pb.v, of0);
            of1 = MFMA32(vf1[S], pb.v, of1);
        }
        __builtin_amdgcn_s_setprio(0);
    }

    float ltot = lsum + __shfl_xor(lsum, 32);
    float inv = 1.f / ltot;
    float* ol = olds + w * (64 * 33);
#pragma unroll
    for (int r = 0; r < 16; ++r) {
        int d = (r & 3) + 8 * (r >> 2) + 4 * hi;
        ol[d * 33 + ln]        = of0[r] * inv;
        ol[(32 + d) * 33 + ln] = of1[r] * inv;
    }
    const unsigned obase = (unsigned)(b * 1024 + qw * 32) * 1024u + h * 64 + l;
#pragma unroll 8
    for (int qq = 0; qq < 32; ++qq)
        out[obase + qq * 1024u] = ol[l * 33 + qq];
}

extern "C" void kernel_launch(void* const* d_in, const int* in_sizes, int n_in,
                              void* d_out, int out_size, void* d_ws, size_t ws_size,
                              hipStream_t stream) {
    const float* x  = (const float*)d_in[0];
    const float* qw = (const float*)d_in[1];
    const float* kw = (const float*)d_in[2];
    const float* vw = (const float*)d_in[3];
    float* out = (float*)d_out;
    char* ws = (char*)d_ws;
    if (ws_size < 67633152u) return;

    bf16_t* xb = (bf16_t*)(ws + XB_OFF);
    bf16_t* wT = (bf16_t*)(ws + WT_OFF);
    bf16_t* Qb = (bf16_t*)(ws + Q_OFF);
    bf16_t* Kb = (bf16_t*)(ws + K_OFF);
    bf16_t* Vt = (bf16_t*)(ws + VT_OFF);

    cast_kernel<<<8448, 256, 0, stream>>>((const float4*)x, (bf16x4*)xb, qw, kw, vw, wT);
    proj_kernel<<<768, 256, 0, stream>>>(xb, wT, Qb, Kb, Vt);
    attn_kernel<<<1024, 256, 0, stream>>>(Qb, Kb, Vt, out);
}